// Round 11
// baseline (140.376 us; speedup 1.0000x reference)
//
#include <hip/hip_runtime.h>
#include <hip/hip_bf16.h>
#include <stdint.h>

#define S_LEN 2048
#define DMODEL 1024
#define NHEAD 16
#define HDIM 64
#define BATCH 2

typedef __bf16 bf16_t;
typedef __attribute__((ext_vector_type(8))) __bf16 bf16x8;
typedef __attribute__((ext_vector_type(4))) __bf16 bf16x4;
typedef __attribute__((ext_vector_type(4))) float f32x4;

#define LOG2E 1.44269504088896340736f

// ---------------- GEMM: C[M][N] = A[M][K] * W[N][K]^T (+bias)*scale
// fp32->bf16 conversion FUSED into LDS staging (reg-stage: float4 x2 -> cvt ->
// ds_write_b128). A may be fp32 or bf16 (template); W is fp32.
// packmode: 0 = linear bf16, 1 = attention-K fragment pack, 2 = V^T fragment pack
template <bool A_F32>
__device__ __forceinline__ void gemm_body(
    const void* __restrict__ Araw, const float* __restrict__ Wf,
    const float* __restrict__ bias, bf16_t* __restrict__ outb,
    float* __restrict__ outf, int M, int N, int K, float scale, int packmode)
{
  __shared__ bf16_t As[128 * 32];
  __shared__ bf16_t Bs[128 * 32];
  int tid = threadIdx.x;
  int w = tid >> 6, lane = tid & 63;
  int lr = lane & 15, lg = lane >> 4;
  int wr = w >> 1, wc = w & 1;
  int m0 = blockIdx.x * 128, n0 = blockIdx.y * 128;

  f32x4 acc[4][4];
#pragma unroll
  for (int a = 0; a < 4; ++a)
#pragma unroll
    for (int bq = 0; bq < 4; ++bq) acc[a][bq] = (f32x4){0.f, 0.f, 0.f, 0.f};

  int col_st = (lane & 3) * 8;

  for (int kt = 0; kt < K; kt += 32) {
    // ---- stage A and W tiles (convert fp32->bf16 in regs)
#pragma unroll
    for (int it = 0; it < 2; ++it) {
      int chunkbase = (w * 2 + it) * 512;          // elems
      int row = (w * 2 + it) * 16 + (lane >> 2);
      // A
      {
        bf16x8 o;
        if constexpr (A_F32) {
          const float* ap = (const float*)Araw + (size_t)(m0 + row) * K + kt + col_st;
          float4 a0 = *reinterpret_cast<const float4*>(ap);
          float4 a1 = *reinterpret_cast<const float4*>(ap + 4);
          o[0] = (bf16_t)a0.x; o[1] = (bf16_t)a0.y; o[2] = (bf16_t)a0.z; o[3] = (bf16_t)a0.w;
          o[4] = (bf16_t)a1.x; o[5] = (bf16_t)a1.y; o[6] = (bf16_t)a1.z; o[7] = (bf16_t)a1.w;
        } else {
          o = *reinterpret_cast<const bf16x8*>(
              (const bf16_t*)Araw + (size_t)(m0 + row) * K + kt + col_st);
        }
        *reinterpret_cast<bf16x8*>(&As[chunkbase + lane * 8]) = o;
      }
      // W (always fp32)
      {
        const float* wp = Wf + (size_t)(n0 + row) * K + kt + col_st;
        float4 w0 = *reinterpret_cast<const float4*>(wp);
        float4 w1 = *reinterpret_cast<const float4*>(wp + 4);
        bf16x8 o;
        o[0] = (bf16_t)w0.x; o[1] = (bf16_t)w0.y; o[2] = (bf16_t)w0.z; o[3] = (bf16_t)w0.w;
        o[4] = (bf16_t)w1.x; o[5] = (bf16_t)w1.y; o[6] = (bf16_t)w1.z; o[7] = (bf16_t)w1.w;
        *reinterpret_cast<bf16x8*>(&Bs[chunkbase + lane * 8]) = o;
      }
    }
    __syncthreads();
    bf16x8 af[4], bfv[4];
#pragma unroll
    for (int mf = 0; mf < 4; ++mf)
      af[mf] = *reinterpret_cast<const bf16x8*>(&As[(wr * 64 + mf * 16 + lr) * 32 + lg * 8]);
#pragma unroll
    for (int nf = 0; nf < 4; ++nf)
      bfv[nf] = *reinterpret_cast<const bf16x8*>(&Bs[(wc * 64 + nf * 16 + lr) * 32 + lg * 8]);
#pragma unroll
    for (int mf = 0; mf < 4; ++mf)
#pragma unroll
      for (int nf = 0; nf < 4; ++nf)
        acc[mf][nf] = __builtin_amdgcn_mfma_f32_16x16x32_bf16(af[mf], bfv[nf], acc[mf][nf], 0, 0, 0);
    __syncthreads();
  }

#pragma unroll
  for (int mf = 0; mf < 4; ++mf) {
#pragma unroll
    for (int nf = 0; nf < 4; ++nf) {
      int col = n0 + wc * 64 + nf * 16 + lr;
      float bcol = bias[col];
#pragma unroll
      for (int i = 0; i < 4; ++i) {
        int row = m0 + wr * 64 + mf * 16 + lg * 4 + i;
        float vv = (acc[mf][nf][i] + bcol) * scale;
        if (outf) {
          outf[(size_t)row * N + col] = vv;
        } else if (packmode == 0) {
          outb[(size_t)row * N + col] = (bf16_t)vv;
        } else if (packmode == 1) {
          // packed K: lane = klg*16 + klr supplies K[kv=kvf*16+klr][half*32+klg*8+j]
          int hh = col >> 6, dh = col & 63;
          int half = dh >> 5, klg = (dh >> 3) & 3, j = dh & 7;
          int bb = row >> 11, s = row & 2047;
          size_t off = ((((size_t)(bb * 16 + hh) * 32 + (s >> 6)) * 4 + ((s >> 4) & 3)) * 2 + half) * 512
                     + (klg * 16 + (s & 15)) * 8 + j;
          outb[off] = (bf16_t)vv;
        } else {
          // packed V^T: lane = vlg*16 + vlr supplies V^T[d=dfo*16+vlr][t64*64+half*32+vlg*8+j]
          int hh = col >> 6, d = col & 63;
          int dfo = d >> 4, vlr = d & 15;
          int bb = row >> 11, s = row & 2047;
          int t64 = s >> 6, sin_ = s & 63;
          int half = sin_ >> 5, vlg = (sin_ >> 3) & 3, j = s & 7;
          size_t off = (((size_t)(bb * 16 + hh) * 32 + t64) * 8 + dfo * 2 + half) * 512
                     + (vlg * 16 + vlr) * 8 + j;
          outb[off] = (bf16_t)vv;
        }
      }
    }
  }
}

__global__ __launch_bounds__(256) void gemm_proj(
    const float* __restrict__ q, const float* __restrict__ k, const float* __restrict__ v,
    const float* __restrict__ wq, const float* __restrict__ wk, const float* __restrict__ wv,
    const float* __restrict__ bq, const float* __restrict__ bk, const float* __restrict__ bv,
    bf16_t* __restrict__ Qp, bf16_t* __restrict__ Kpk, bf16_t* __restrict__ Vpk)
{
  int z = blockIdx.z;
  const float* A = (z == 0) ? q : (z == 1) ? k : v;
  const float* W = (z == 0) ? wq : (z == 1) ? wk : wv;
  const float* bias = (z == 0) ? bq : (z == 1) ? bk : bv;
  bf16_t* o = (z == 0) ? Qp : (z == 1) ? Kpk : Vpk;
  // fold 1/sqrt(64) AND log2(e) into Q so attention can use raw exp2
  float scale = (z == 0) ? 0.125f * LOG2E : 1.0f;
  gemm_body<true>(A, W, bias, o, nullptr, BATCH * S_LEN, DMODEL, DMODEL, scale, z);
}

__global__ __launch_bounds__(256) void gemm_out(
    const bf16_t* __restrict__ O, const float* __restrict__ wo,
    const float* __restrict__ bo, float* __restrict__ out)
{
  gemm_body<false>(O, wo, bo, nullptr, out, BATCH * S_LEN, DMODEL, DMODEL, 1.0f, 0);
}

// ---------------- causal flash attention: fragment-packed K/V, barrier-free,
// 32 q-rows per wave (two 16-row Q fragments share each K/V fragment fetch).
// grid 256 = 32 bh x 8 j; 512 thr = 8 free-running waves: waves 0-3 own
// 128-row tile j (32 rows each), waves 4-7 own tile 15-j (block trips == 34).
// flat%8 == bh%8 -> one bh per XCD group.
#define PSTRIDE 66

__global__ __launch_bounds__(512, 2) void attn_fwd(
    const bf16_t* __restrict__ Qp, const bf16_t* __restrict__ Kpk,
    const bf16_t* __restrict__ Vpk, bf16_t* __restrict__ O)
{
  int flat = blockIdx.x;
  int bh = flat & 31, j = flat >> 5;
  int b = bh >> 4, h = bh & 15;
  int tid = threadIdx.x, wv = tid >> 6, lane = tid & 63;
  int lr = lane & 15, lg = lane >> 4;
  int grp = wv >> 2, wl = wv & 3;

  __shared__ bf16_t Ps[8][2][16 * PSTRIDE];

  int qtile = grp ? (15 - j) : j;          // 128-row tile
  int rbase = qtile * 128 + wl * 32;       // wave's first q row (32 rows)
  int t_end = (rbase + 31) >> 6;           // wave's diagonal kv tile (uniform)

  // two 16-row Q fragments
  bf16x8 qf[2][2];
#pragma unroll
  for (int g = 0; g < 2; ++g) {
    const bf16_t* Qb = Qp + ((size_t)b * S_LEN + rbase + g * 16 + lr) * DMODEL + h * HDIM + lg * 8;
    qf[g][0] = *reinterpret_cast<const bf16x8*>(Qb);
    qf[g][1] = *reinterpret_cast<const bf16x8*>(Qb + 32);
  }

  f32x4 oacc0[4], oacc1[4];
#pragma unroll
  for (int df = 0; df < 4; ++df) {
    oacc0[df] = (f32x4){0.f, 0.f, 0.f, 0.f};
    oacc1[df] = (f32x4){0.f, 0.f, 0.f, 0.f};
  }
  float m0 = -1e30f, l0 = 0.f, m1 = -1e30f, l1 = 0.f;

  const bf16_t* Kb = Kpk + (size_t)bh * (32 * 4096) + lane * 8;
  const bf16_t* Vb = Vpk + (size_t)bh * (32 * 4096) + lane * 8;
  bf16_t* ps0 = &Ps[wv][0][lr * PSTRIDE];
  bf16_t* ps1 = &Ps[wv][1][lr * PSTRIDE];

  for (int t = 0; t <= t_end; ++t) {
    const bf16_t* Kt = Kb + t * 4096;
    const bf16_t* Vt_ = Vb + t * 4096;

    // ---- K and V fragment loads (16 outstanding, coalesced, serve 32 rows)
    bf16x8 kf[8];
#pragma unroll
    for (int f = 0; f < 8; ++f)
      kf[f] = *reinterpret_cast<const bf16x8*>(Kt + f * 512);
    bf16x8 vf[8];
#pragma unroll
    for (int f = 0; f < 8; ++f)
      vf[f] = *reinterpret_cast<const bf16x8*>(Vt_ + f * 512);

    // ---- S^T = K Q^T for both row-groups (16 MFMA)
    f32x4 sa0[4], sa1[4];
    __builtin_amdgcn_s_setprio(1);
#pragma unroll
    for (int kvf = 0; kvf < 4; ++kvf) {
      f32x4 s = (f32x4){0.f, 0.f, 0.f, 0.f};
      s = __builtin_amdgcn_mfma_f32_16x16x32_bf16(kf[kvf * 2 + 0], qf[0][0], s, 0, 0, 0);
      s = __builtin_amdgcn_mfma_f32_16x16x32_bf16(kf[kvf * 2 + 1], qf[0][1], s, 0, 0, 0);
      sa0[kvf] = s;
      f32x4 s2 = (f32x4){0.f, 0.f, 0.f, 0.f};
      s2 = __builtin_amdgcn_mfma_f32_16x16x32_bf16(kf[kvf * 2 + 0], qf[1][0], s2, 0, 0, 0);
      s2 = __builtin_amdgcn_mfma_f32_16x16x32_bf16(kf[kvf * 2 + 1], qf[1][1], s2, 0, 0, 0);
      sa1[kvf] = s2;
    }
    __builtin_amdgcn_s_setprio(0);

    // ---- causal mask (wave's diagonal tile; lane: q=lr, kv=kvf*16+lg*4+i)
    if (t == t_end) {
      int kv0 = t * 64;
#pragma unroll
      for (int kvf = 0; kvf < 4; ++kvf) {
        int kv_g = kv0 + kvf * 16 + lg * 4;
#pragma unroll
        for (int i = 0; i < 4; ++i) {
          if (kv_g + i > rbase + lr)      sa0[kvf][i] = -1e30f;
          if (kv_g + i > rbase + 16 + lr) sa1[kvf][i] = -1e30f;
        }
      }
    }

    // ---- defer-max online softmax, group 0
    {
      float lmax = fmaxf(fmaxf(sa0[0][0], sa0[0][1]), fmaxf(sa0[0][2], sa0[0][3]));
#pragma unroll
      for (int kvf = 1; kvf < 4; ++kvf)
        lmax = fmaxf(lmax, fmaxf(fmaxf(sa0[kvf][0], sa0[kvf][1]),
                                 fmaxf(sa0[kvf][2], sa0[kvf][3])));
      if (__any(lmax > m0 + 8.f)) {
        float mx = lmax;
        mx = fmaxf(mx, __shfl_xor(mx, 16));
        mx = fmaxf(mx, __shfl_xor(mx, 32));
        float mn = fmaxf(m0, mx);
        float rsc = __builtin_amdgcn_exp2f(m0 - mn);
        m0 = mn; l0 *= rsc;
#pragma unroll
        for (int dfo = 0; dfo < 4; ++dfo) oacc0[dfo] *= rsc;
      }
      float psum = 0.f;
#pragma unroll
      for (int kvf = 0; kvf < 4; ++kvf) {
        bf16x4 pw;
#pragma unroll
        for (int i = 0; i < 4; ++i) {
          float p = __builtin_amdgcn_exp2f(sa0[kvf][i] - m0);
          psum += p;
          pw[i] = (bf16_t)p;
        }
        *reinterpret_cast<bf16x4*>(ps0 + kvf * 16 + lg * 4) = pw;
      }
      l0 += psum;
    }
    // ---- group 1
    {
      float lmax = fmaxf(fmaxf(sa1[0][0], sa1[0][1]), fmaxf(sa1[0][2], sa1[0][3]));
#pragma unroll
      for (int kvf = 1; kvf < 4; ++kvf)
        lmax = fmaxf(lmax, fmaxf(fmaxf(sa1[kvf][0], sa1[kvf][1]),
                                 fmaxf(sa1[kvf][2], sa1[kvf][3])));
      if (__any(lmax > m1 + 8.f)) {
        float mx = lmax;
        mx = fmaxf(mx, __shfl_xor(mx, 16));
        mx = fmaxf(mx, __shfl_xor(mx, 32));
        float mn = fmaxf(m1, mx);
        float rsc = __builtin_amdgcn_exp2f(m1 - mn);
        m1 = mn; l1 *= rsc;
#pragma unroll
        for (int dfo = 0; dfo < 4; ++dfo) oacc1[dfo] *= rsc;
      }
      float psum = 0.f;
#pragma unroll
      for (int kvf = 0; kvf < 4; ++kvf) {
        bf16x4 pw;
#pragma unroll
        for (int i = 0; i < 4; ++i) {
          float p = __builtin_amdgcn_exp2f(sa1[kvf][i] - m1);
          psum += p;
          pw[i] = (bf16_t)p;
        }
        *reinterpret_cast<bf16x4*>(ps1 + kvf * 16 + lg * 4) = pw;
      }
      l1 += psum;
    }

    // wait this wave's P writes; fence scheduler (rule #18)
    asm volatile("s_waitcnt lgkmcnt(0)" ::: "memory");
    __builtin_amdgcn_sched_barrier(0);

    bf16x8 pa00 = *reinterpret_cast<const bf16x8*>(ps0 + lg * 8);
    bf16x8 pa01 = *reinterpret_cast<const bf16x8*>(ps0 + 32 + lg * 8);
    bf16x8 pa10 = *reinterpret_cast<const bf16x8*>(ps1 + lg * 8);
    bf16x8 pa11 = *reinterpret_cast<const bf16x8*>(ps1 + 32 + lg * 8);
    __builtin_amdgcn_s_setprio(1);
#pragma unroll
    for (int dfo = 0; dfo < 4; ++dfo) {
      oacc0[dfo] = __builtin_amdgcn_mfma_f32_16x16x32_bf16(vf[dfo * 2 + 0], pa00, oacc0[dfo], 0, 0, 0);
      oacc0[dfo] = __builtin_amdgcn_mfma_f32_16x16x32_bf16(vf[dfo * 2 + 1], pa01, oacc0[dfo], 0, 0, 0);
      oacc1[dfo] = __builtin_amdgcn_mfma_f32_16x16x32_bf16(vf[dfo * 2 + 0], pa10, oacc1[dfo], 0, 0, 0);
      oacc1[dfo] = __builtin_amdgcn_mfma_f32_16x16x32_bf16(vf[dfo * 2 + 1], pa11, oacc1[dfo], 0, 0, 0);
    }
    __builtin_amdgcn_s_setprio(0);
  }

  // ---- row-sum reduce, normalize, write O (both groups)
  l0 += __shfl_xor(l0, 16);
  l0 += __shfl_xor(l0, 32);
  l1 += __shfl_xor(l1, 16);
  l1 += __shfl_xor(l1, 32);
  float inv0 = 1.0f / l0, inv1 = 1.0f / l1;
  bf16_t* ob0 = O + ((size_t)b * S_LEN + rbase + lr) * DMODEL + h * HDIM + lg * 4;
  bf16_t* ob1 = O + ((size_t)b * S_LEN + rbase + 16 + lr) * DMODEL + h * HDIM + lg * 4;
#pragma unroll
  for (int dfo = 0; dfo < 4; ++dfo) {
    bf16x4 ov0, ov1;
#pragma unroll
    for (int i = 0; i < 4; ++i) {
      ov0[i] = (bf16_t)(oacc0[dfo][i] * inv0);
      ov1[i] = (bf16_t)(oacc1[dfo][i] * inv1);
    }
    *reinterpret_cast<bf16x4*>(ob0 + dfo * 16) = ov0;
    *reinterpret_cast<bf16x4*>(ob1 + dfo * 16) = ov1;
  }
}

extern "C" void kernel_launch(void* const* d_in, const int* in_sizes, int n_in,
                              void* d_out, int out_size, void* d_ws, size_t ws_size,
                              hipStream_t stream) {
  const float* q  = (const float*)d_in[0];
  const float* k  = (const float*)d_in[1];
  const float* v  = (const float*)d_in[2];
  // d_in[3] = mask (known causal tril; hard-coded)
  const float* Wq = (const float*)d_in[4];
  const float* bq = (const float*)d_in[5];
  const float* Wk = (const float*)d_in[6];
  const float* bk = (const float*)d_in[7];
  const float* Wv = (const float*)d_in[8];
  const float* bv = (const float*)d_in[9];
  const float* Wo = (const float*)d_in[10];
  const float* bo = (const float*)d_in[11];
  float* out = (float*)d_out;

  const size_t MB = 1u << 20;
  char* base = (char*)d_ws;
  bf16_t* Qp  = (bf16_t*)(base + 0 * MB);
  bf16_t* Kpk = (bf16_t*)(base + 8 * MB);
  bf16_t* Vpk = (bf16_t*)(base + 16 * MB);
  bf16_t* Ob  = (bf16_t*)(base + 24 * MB);

  gemm_proj<<<dim3(32, 8, 3), 256, 0, stream>>>(q, k, v, Wq, Wk, Wv,
                                                bq, bk, bv, Qp, Kpk, Vpk);
  attn_fwd<<<256, 512, 0, stream>>>(Qp, Kpk, Vpk, Ob);
  gemm_out<<<dim3(32, 8), 256, 0, stream>>>(Ob, Wo, bo, out);
}

// Round 12
// 132.023 us; speedup vs baseline: 1.0633x; 1.0633x over previous
//
#include <hip/hip_runtime.h>
#include <hip/hip_bf16.h>
#include <stdint.h>

#define S_LEN 2048
#define DMODEL 1024
#define NHEAD 16
#define HDIM 64
#define BATCH 2

typedef __bf16 bf16_t;
typedef __attribute__((ext_vector_type(8))) __bf16 bf16x8;
typedef __attribute__((ext_vector_type(4))) __bf16 bf16x4;
typedef __attribute__((ext_vector_type(4))) float f32x4;

#define LOG2E 1.44269504088896340736f

__device__ __forceinline__ void gload_lds16(const void* g, void* l) {
  __builtin_amdgcn_global_load_lds(
      (const __attribute__((address_space(1))) uint32_t*)g,
      (__attribute__((address_space(3))) uint32_t*)l, 16, 0, 0);
}

// ---------------- fp32 -> bf16 conversion of q,k,v and the 4 weight matrices
__global__ __launch_bounds__(256) void convert_all(
    const float* __restrict__ q, const float* __restrict__ k, const float* __restrict__ v,
    const float* __restrict__ wq, const float* __restrict__ wk, const float* __restrict__ wv,
    const float* __restrict__ wo,
    bf16_t* __restrict__ qb, bf16_t* __restrict__ kb, bf16_t* __restrict__ vb,
    bf16_t* __restrict__ wqb, bf16_t* __restrict__ wkb, bf16_t* __restrict__ wvb,
    bf16_t* __restrict__ wob)
{
  const size_t M1 = 1048576;
  size_t e = ((size_t)blockIdx.x * 256 + threadIdx.x) * 4;
  const float* src; bf16_t* dst; size_t off;
  if      (e <  4*M1) { src = q;  dst = qb;  off = e;         }
  else if (e <  8*M1) { src = k;  dst = kb;  off = e - 4*M1;  }
  else if (e < 12*M1) { src = v;  dst = vb;  off = e - 8*M1;  }
  else if (e < 13*M1) { src = wq; dst = wqb; off = e - 12*M1; }
  else if (e < 14*M1) { src = wk; dst = wkb; off = e - 13*M1; }
  else if (e < 15*M1) { src = wv; dst = wvb; off = e - 14*M1; }
  else                { src = wo; dst = wob; off = e - 15*M1; }
  float4 f = *reinterpret_cast<const float4*>(src + off);
  bf16x4 o;
  o[0] = (bf16_t)f.x; o[1] = (bf16_t)f.y; o[2] = (bf16_t)f.z; o[3] = (bf16_t)f.w;
  *reinterpret_cast<bf16x4*>(dst + off) = o;
}

// ---------------- GEMM: C[M][N] = A[M][K] * W[N][K]^T (+bias)*scale
// packmode: 0 = linear bf16, 1 = attention-K fragment pack, 2 = V^T fragment pack
__device__ __forceinline__ void gemm_body(
    const bf16_t* __restrict__ A, const bf16_t* __restrict__ W,
    const float* __restrict__ bias, bf16_t* __restrict__ outb,
    float* __restrict__ outf, int M, int N, int K, float scale, int packmode)
{
  __shared__ bf16_t As[128 * 32];
  __shared__ bf16_t Bs[128 * 32];
  int tid = threadIdx.x;
  int w = tid >> 6, lane = tid & 63;
  int lr = lane & 15, lg = lane >> 4;
  int wr = w >> 1, wc = w & 1;
  int m0 = blockIdx.x * 128, n0 = blockIdx.y * 128;

  f32x4 acc[4][4];
#pragma unroll
  for (int a = 0; a < 4; ++a)
#pragma unroll
    for (int bq = 0; bq < 4; ++bq) acc[a][bq] = (f32x4){0.f, 0.f, 0.f, 0.f};

  int col_st = (lane & 3) * 8;

  for (int kt = 0; kt < K; kt += 32) {
#pragma unroll
    for (int it = 0; it < 2; ++it) {
      int chunkbase = (w * 2 + it) * 512;
      int row = (w * 2 + it) * 16 + (lane >> 2);
      gload_lds16(A + (size_t)(m0 + row) * K + kt + col_st, &As[chunkbase]);
      gload_lds16(W + (size_t)(n0 + row) * K + kt + col_st, &Bs[chunkbase]);
    }
    __syncthreads();
    bf16x8 af[4], bfv[4];
#pragma unroll
    for (int mf = 0; mf < 4; ++mf)
      af[mf] = *reinterpret_cast<const bf16x8*>(&As[(wr * 64 + mf * 16 + lr) * 32 + lg * 8]);
#pragma unroll
    for (int nf = 0; nf < 4; ++nf)
      bfv[nf] = *reinterpret_cast<const bf16x8*>(&Bs[(wc * 64 + nf * 16 + lr) * 32 + lg * 8]);
#pragma unroll
    for (int mf = 0; mf < 4; ++mf)
#pragma unroll
      for (int nf = 0; nf < 4; ++nf)
        acc[mf][nf] = __builtin_amdgcn_mfma_f32_16x16x32_bf16(af[mf], bfv[nf], acc[mf][nf], 0, 0, 0);
    __syncthreads();
  }

#pragma unroll
  for (int mf = 0; mf < 4; ++mf) {
#pragma unroll
    for (int nf = 0; nf < 4; ++nf) {
      int col = n0 + wc * 64 + nf * 16 + lr;
      float bcol = bias[col];
#pragma unroll
      for (int i = 0; i < 4; ++i) {
        int row = m0 + wr * 64 + mf * 16 + lg * 4 + i;
        float vv = (acc[mf][nf][i] + bcol) * scale;
        if (outf) {
          outf[(size_t)row * N + col] = vv;
        } else if (packmode == 0) {
          outb[(size_t)row * N + col] = (bf16_t)vv;
        } else if (packmode == 1) {
          // packed K: lane = klg*16 + klr supplies K[kv=kvf*16+klr][half*32+klg*8+j]
          int hh = col >> 6, dh = col & 63;
          int half = dh >> 5, klg = (dh >> 3) & 3, j = dh & 7;
          int bb = row >> 11, s = row & 2047;
          size_t off = ((((size_t)(bb * 16 + hh) * 32 + (s >> 6)) * 4 + ((s >> 4) & 3)) * 2 + half) * 512
                     + (klg * 16 + (s & 15)) * 8 + j;
          outb[off] = (bf16_t)vv;
        } else {
          // packed V^T: lane = vlg*16 + vlr supplies V^T[d=dfo*16+vlr][t64*64+half*32+vlg*8+j]
          int hh = col >> 6, d = col & 63;
          int dfo = d >> 4, vlr = d & 15;
          int bb = row >> 11, s = row & 2047;
          int t64 = s >> 6, sin_ = s & 63;
          int half = sin_ >> 5, vlg = (sin_ >> 3) & 3, j = s & 7;
          size_t off = (((size_t)(bb * 16 + hh) * 32 + t64) * 8 + dfo * 2 + half) * 512
                     + (vlg * 16 + vlr) * 8 + j;
          outb[off] = (bf16_t)vv;
        }
      }
    }
  }
}

__global__ __launch_bounds__(256) void gemm_proj(
    const bf16_t* __restrict__ qb, const bf16_t* __restrict__ kb, const bf16_t* __restrict__ vb,
    const bf16_t* __restrict__ wqb, const bf16_t* __restrict__ wkb, const bf16_t* __restrict__ wvb,
    const float* __restrict__ bq, const float* __restrict__ bk, const float* __restrict__ bv,
    bf16_t* __restrict__ Qp, bf16_t* __restrict__ Kpk, bf16_t* __restrict__ Vpk)
{
  int z = blockIdx.z;
  const bf16_t* A = (z == 0) ? qb : (z == 1) ? kb : vb;
  const bf16_t* W = (z == 0) ? wqb : (z == 1) ? wkb : wvb;
  const float* bias = (z == 0) ? bq : (z == 1) ? bk : bv;
  bf16_t* o = (z == 0) ? Qp : (z == 1) ? Kpk : Vpk;
  // fold 1/sqrt(64) AND log2(e) into Q so attention can use raw exp2
  float scale = (z == 0) ? 0.125f * LOG2E : 1.0f;
  gemm_body(A, W, bias, o, nullptr, BATCH * S_LEN, DMODEL, DMODEL, scale, z);
}

__global__ __launch_bounds__(256) void gemm_out(
    const bf16_t* __restrict__ O, const bf16_t* __restrict__ wob,
    const float* __restrict__ bo, float* __restrict__ out)
{
  gemm_body(O, wob, bo, nullptr, out, BATCH * S_LEN, DMODEL, DMODEL, 1.0f, 0);
}

// ---------------- causal flash attention: fragment-packed K/V, 32 q-rows/wave,
// UNIFORM-TRIP schedule. grid 512 = 32 bh x 16 qp; block = 256 thr = 4 waves
// {slice s in 0..1} x {kv-half h in 0..1}. Each wave runs 2 phases: 64-row
// tile qp then tile 31-qp, over its kv-half. Trips/wave = ceil((qp+1)/2) +
// ceil((32-qp)/2) ~= 17 for EVERY wave -> both waves/SIMD alive to the end
// (fixes the measured 1.08 waves/SIMD short+long pathology of rounds 5/10).
// Halves merge (m,l,oacc) via padded LDS once per phase (2 syncthreads).
#define PSTRIDE 66

__global__ __launch_bounds__(256, 2) void attn_fwd(
    const bf16_t* __restrict__ Qp, const bf16_t* __restrict__ Kpk,
    const bf16_t* __restrict__ Vpk, bf16_t* __restrict__ O)
{
  int flat = blockIdx.x;
  int bh = flat & 31, qp = flat >> 5;      // bh inner: flat%8 == bh%8 (XCD)
  int b = bh >> 4, h = bh & 15;
  int tid = threadIdx.x, wv = tid >> 6, lane = tid & 63;
  int lr = lane & 15, lg = lane >> 4;
  int s = wv >> 1, hf = wv & 1;

  __shared__ bf16_t Ps[4][2][16 * PSTRIDE];
  __shared__ float Mm[2][2][64];
  __shared__ float Lm[2][2][64];
  __shared__ float Om[2][2][64][17];       // stride 17: conflict-free

  const bf16_t* Kb = Kpk + (size_t)bh * (32 * 4096) + lane * 8;
  const bf16_t* Vb = Vpk + (size_t)bh * (32 * 4096) + lane * 8;
  bf16_t* ps0 = &Ps[wv][0][lr * PSTRIDE];
  bf16_t* ps1 = &Ps[wv][1][lr * PSTRIDE];

  for (int p = 0; p < 2; ++p) {
    int qt = p ? (31 - qp) : qp;
    int rbase = qt * 64 + s * 32;
    int nt = qt + 1;
    int hsp = (nt + 1) >> 1;
    int t0 = hf ? hsp : 0;
    int t1 = hf ? nt : hsp;

    // two 16-row Q fragments for this phase
    bf16x8 qf[2][2];
#pragma unroll
    for (int g = 0; g < 2; ++g) {
      const bf16_t* Qb = Qp + ((size_t)b * S_LEN + rbase + g * 16 + lr) * DMODEL + h * HDIM + lg * 8;
      qf[g][0] = *reinterpret_cast<const bf16x8*>(Qb);
      qf[g][1] = *reinterpret_cast<const bf16x8*>(Qb + 32);
    }

    f32x4 oacc0[4], oacc1[4];
#pragma unroll
    for (int df = 0; df < 4; ++df) {
      oacc0[df] = (f32x4){0.f, 0.f, 0.f, 0.f};
      oacc1[df] = (f32x4){0.f, 0.f, 0.f, 0.f};
    }
    float m0 = -1e30f, l0 = 0.f, m1 = -1e30f, l1 = 0.f;

    for (int t = t0; t < t1; ++t) {
      const bf16_t* Kt = Kb + t * 4096;
      const bf16_t* Vt_ = Vb + t * 4096;

      bf16x8 kf[8];
#pragma unroll
      for (int f = 0; f < 8; ++f)
        kf[f] = *reinterpret_cast<const bf16x8*>(Kt + f * 512);
      bf16x8 vf[8];
#pragma unroll
      for (int f = 0; f < 8; ++f)
        vf[f] = *reinterpret_cast<const bf16x8*>(Vt_ + f * 512);

      // ---- S^T = K Q^T for both row-groups (16 MFMA)
      f32x4 sa0[4], sa1[4];
      __builtin_amdgcn_s_setprio(1);
#pragma unroll
      for (int kvf = 0; kvf < 4; ++kvf) {
        f32x4 sv = (f32x4){0.f, 0.f, 0.f, 0.f};
        sv = __builtin_amdgcn_mfma_f32_16x16x32_bf16(kf[kvf * 2 + 0], qf[0][0], sv, 0, 0, 0);
        sv = __builtin_amdgcn_mfma_f32_16x16x32_bf16(kf[kvf * 2 + 1], qf[0][1], sv, 0, 0, 0);
        sa0[kvf] = sv;
        f32x4 sv2 = (f32x4){0.f, 0.f, 0.f, 0.f};
        sv2 = __builtin_amdgcn_mfma_f32_16x16x32_bf16(kf[kvf * 2 + 0], qf[1][0], sv2, 0, 0, 0);
        sv2 = __builtin_amdgcn_mfma_f32_16x16x32_bf16(kf[kvf * 2 + 1], qf[1][1], sv2, 0, 0, 0);
        sa1[kvf] = sv2;
      }
      __builtin_amdgcn_s_setprio(0);

      // ---- causal mask (diagonal tile; lane: q=lr, kv=kvf*16+lg*4+i)
      if (t == qt) {
        int kv0 = t * 64;
#pragma unroll
        for (int kvf = 0; kvf < 4; ++kvf) {
          int kv_g = kv0 + kvf * 16 + lg * 4;
#pragma unroll
          for (int i = 0; i < 4; ++i) {
            if (kv_g + i > rbase + lr)      sa0[kvf][i] = -1e30f;
            if (kv_g + i > rbase + 16 + lr) sa1[kvf][i] = -1e30f;
          }
        }
      }

      // ---- defer-max online softmax, group 0
      {
        float lmax = fmaxf(fmaxf(sa0[0][0], sa0[0][1]), fmaxf(sa0[0][2], sa0[0][3]));
#pragma unroll
        for (int kvf = 1; kvf < 4; ++kvf)
          lmax = fmaxf(lmax, fmaxf(fmaxf(sa0[kvf][0], sa0[kvf][1]),
                                   fmaxf(sa0[kvf][2], sa0[kvf][3])));
        if (__any(lmax > m0 + 8.f)) {
          float mx = lmax;
          mx = fmaxf(mx, __shfl_xor(mx, 16));
          mx = fmaxf(mx, __shfl_xor(mx, 32));
          float mn = fmaxf(m0, mx);
          float rsc = __builtin_amdgcn_exp2f(m0 - mn);
          m0 = mn; l0 *= rsc;
#pragma unroll
          for (int dfo = 0; dfo < 4; ++dfo) oacc0[dfo] *= rsc;
        }
        float psum = 0.f;
#pragma unroll
        for (int kvf = 0; kvf < 4; ++kvf) {
          bf16x4 pw;
#pragma unroll
          for (int i = 0; i < 4; ++i) {
            float pe = __builtin_amdgcn_exp2f(sa0[kvf][i] - m0);
            psum += pe;
            pw[i] = (bf16_t)pe;
          }
          *reinterpret_cast<bf16x4*>(ps0 + kvf * 16 + lg * 4) = pw;
        }
        l0 += psum;
      }
      // ---- group 1
      {
        float lmax = fmaxf(fmaxf(sa1[0][0], sa1[0][1]), fmaxf(sa1[0][2], sa1[0][3]));
#pragma unroll
        for (int kvf = 1; kvf < 4; ++kvf)
          lmax = fmaxf(lmax, fmaxf(fmaxf(sa1[kvf][0], sa1[kvf][1]),
                                   fmaxf(sa1[kvf][2], sa1[kvf][3])));
        if (__any(lmax > m1 + 8.f)) {
          float mx = lmax;
          mx = fmaxf(mx, __shfl_xor(mx, 16));
          mx = fmaxf(mx, __shfl_xor(mx, 32));
          float mn = fmaxf(m1, mx);
          float rsc = __builtin_amdgcn_exp2f(m1 - mn);
          m1 = mn; l1 *= rsc;
#pragma unroll
          for (int dfo = 0; dfo < 4; ++dfo) oacc1[dfo] *= rsc;
        }
        float psum = 0.f;
#pragma unroll
        for (int kvf = 0; kvf < 4; ++kvf) {
          bf16x4 pw;
#pragma unroll
          for (int i = 0; i < 4; ++i) {
            float pe = __builtin_amdgcn_exp2f(sa1[kvf][i] - m1);
            psum += pe;
            pw[i] = (bf16_t)pe;
          }
          *reinterpret_cast<bf16x4*>(ps1 + kvf * 16 + lg * 4) = pw;
        }
        l1 += psum;
      }

      // wait this wave's P writes; fence scheduler (rule #18)
      asm volatile("s_waitcnt lgkmcnt(0)" ::: "memory");
      __builtin_amdgcn_sched_barrier(0);

      bf16x8 pa00 = *reinterpret_cast<const bf16x8*>(ps0 + lg * 8);
      bf16x8 pa01 = *reinterpret_cast<const bf16x8*>(ps0 + 32 + lg * 8);
      bf16x8 pa10 = *reinterpret_cast<const bf16x8*>(ps1 + lg * 8);
      bf16x8 pa11 = *reinterpret_cast<const bf16x8*>(ps1 + 32 + lg * 8);
      __builtin_amdgcn_s_setprio(1);
#pragma unroll
      for (int dfo = 0; dfo < 4; ++dfo) {
        oacc0[dfo] = __builtin_amdgcn_mfma_f32_16x16x32_bf16(vf[dfo * 2 + 0], pa00, oacc0[dfo], 0, 0, 0);
        oacc0[dfo] = __builtin_amdgcn_mfma_f32_16x16x32_bf16(vf[dfo * 2 + 1], pa01, oacc0[dfo], 0, 0, 0);
        oacc1[dfo] = __builtin_amdgcn_mfma_f32_16x16x32_bf16(vf[dfo * 2 + 0], pa10, oacc1[dfo], 0, 0, 0);
        oacc1[dfo] = __builtin_amdgcn_mfma_f32_16x16x32_bf16(vf[dfo * 2 + 1], pa11, oacc1[dfo], 0, 0, 0);
      }
      __builtin_amdgcn_s_setprio(0);
    }

    // ---- kv-half merge: h=1 publishes, h=0 combines and writes O
    if (hf) {
      Mm[s][0][lane] = m0; Lm[s][0][lane] = l0;
      Mm[s][1][lane] = m1; Lm[s][1][lane] = l1;
#pragma unroll
      for (int dfo = 0; dfo < 4; ++dfo)
#pragma unroll
        for (int i = 0; i < 4; ++i) {
          Om[s][0][lane][dfo * 4 + i] = oacc0[dfo][i];
          Om[s][1][lane][dfo * 4 + i] = oacc1[dfo][i];
        }
    }
    __syncthreads();
    if (!hf) {
      // group 0
      {
        float mB = Mm[s][0][lane], lB = Lm[s][0][lane];
        float mAB = fmaxf(m0, mB);
        float fA = __builtin_amdgcn_exp2f(m0 - mAB);
        float fB = __builtin_amdgcn_exp2f(mB - mAB);
        l0 = l0 * fA + lB * fB;
#pragma unroll
        for (int dfo = 0; dfo < 4; ++dfo)
#pragma unroll
          for (int i = 0; i < 4; ++i)
            oacc0[dfo][i] = oacc0[dfo][i] * fA + Om[s][0][lane][dfo * 4 + i] * fB;
      }
      // group 1
      {
        float mB = Mm[s][1][lane], lB = Lm[s][1][lane];
        float mAB = fmaxf(m1, mB);
        float fA = __builtin_amdgcn_exp2f(m1 - mAB);
        float fB = __builtin_amdgcn_exp2f(mB - mAB);
        l1 = l1 * fA + lB * fB;
#pragma unroll
        for (int dfo = 0; dfo < 4; ++dfo)
#pragma unroll
          for (int i = 0; i < 4; ++i)
            oacc1[dfo][i] = oacc1[dfo][i] * fA + Om[s][1][lane][dfo * 4 + i] * fB;
      }

      l0 += __shfl_xor(l0, 16);
      l0 += __shfl_xor(l0, 32);
      l1 += __shfl_xor(l1, 16);
      l1 += __shfl_xor(l1, 32);
      float inv0 = 1.0f / l0, inv1 = 1.0f / l1;
      bf16_t* ob0 = O + ((size_t)b * S_LEN + rbase + lr) * DMODEL + h * HDIM + lg * 4;
      bf16_t* ob1 = O + ((size_t)b * S_LEN + rbase + 16 + lr) * DMODEL + h * HDIM + lg * 4;
#pragma unroll
      for (int dfo = 0; dfo < 4; ++dfo) {
        bf16x4 ov0, ov1;
#pragma unroll
        for (int i = 0; i < 4; ++i) {
          ov0[i] = (bf16_t)(oacc0[dfo][i] * inv0);
          ov1[i] = (bf16_t)(oacc1[dfo][i] * inv1);
        }
        *reinterpret_cast<bf16x4*>(ob0 + dfo * 16) = ov0;
        *reinterpret_cast<bf16x4*>(ob1 + dfo * 16) = ov1;
      }
    }
    __syncthreads();   // Mm/Lm/Om free for next phase
  }
}

extern "C" void kernel_launch(void* const* d_in, const int* in_sizes, int n_in,
                              void* d_out, int out_size, void* d_ws, size_t ws_size,
                              hipStream_t stream) {
  const float* q  = (const float*)d_in[0];
  const float* k  = (const float*)d_in[1];
  const float* v  = (const float*)d_in[2];
  // d_in[3] = mask (known causal tril; hard-coded)
  const float* Wq = (const float*)d_in[4];
  const float* bq = (const float*)d_in[5];
  const float* Wk = (const float*)d_in[6];
  const float* bk = (const float*)d_in[7];
  const float* Wv = (const float*)d_in[8];
  const float* bv = (const float*)d_in[9];
  const float* Wo = (const float*)d_in[10];
  const float* bo = (const float*)d_in[11];
  float* out = (float*)d_out;

  const size_t MB = 1u << 20;
  char* base = (char*)d_ws;
  bf16_t* qb  = (bf16_t*)(base + 0 * MB);
  bf16_t* kb  = (bf16_t*)(base + 8 * MB);
  bf16_t* vb  = (bf16_t*)(base + 16 * MB);
  bf16_t* wqb = (bf16_t*)(base + 24 * MB);
  bf16_t* wkb = (bf16_t*)(base + 26 * MB);
  bf16_t* wvb = (bf16_t*)(base + 28 * MB);
  bf16_t* wob = (bf16_t*)(base + 30 * MB);
  bf16_t* Qp  = (bf16_t*)(base + 32 * MB);
  bf16_t* Kpk = (bf16_t*)(base + 40 * MB);
  bf16_t* Vpk = (bf16_t*)(base + 48 * MB);
  bf16_t* Ob  = (bf16_t*)(base + 56 * MB);

  convert_all<<<16384, 256, 0, stream>>>(q, k, v, Wq, Wk, Wv, Wo,
                                         qb, kb, vb, wqb, wkb, wvb, wob);
  gemm_proj<<<dim3(32, 8, 3), 256, 0, stream>>>(qb, kb, vb, wqb, wkb, wvb,
                                                bq, bk, bv, Qp, Kpk, Vpk);
  attn_fwd<<<512, 256, 0, stream>>>(Qp, Kpk, Vpk, Ob);
  gemm_out<<<dim3(32, 8), 256, 0, stream>>>(Ob, wob, bo, out);
}

// Round 13
// 113.378 us; speedup vs baseline: 1.2381x; 1.1644x over previous
//
#include <hip/hip_runtime.h>
#include <hip/hip_bf16.h>
#include <stdint.h>

#define S_LEN 2048
#define DMODEL 1024
#define NHEAD 16
#define HDIM 64
#define BATCH 2

typedef __bf16 bf16_t;
typedef __attribute__((ext_vector_type(8))) __bf16 bf16x8;
typedef __attribute__((ext_vector_type(4))) __bf16 bf16x4;
typedef __attribute__((ext_vector_type(4))) float f32x4;
typedef __attribute__((ext_vector_type(16))) float f32x16;
typedef __attribute__((ext_vector_type(4))) uint32_t u32x4;

#define LOG2E 1.44269504088896340736f

__device__ __forceinline__ void gload_lds16(const void* g, void* l) {
  __builtin_amdgcn_global_load_lds(
      (const __attribute__((address_space(1))) uint32_t*)g,
      (__attribute__((address_space(3))) uint32_t*)l, 16, 0, 0);
}

// ---------------- fp32 -> bf16 conversion of q,k,v and the 4 weight matrices
__global__ __launch_bounds__(256) void convert_all(
    const float* __restrict__ q, const float* __restrict__ k, const float* __restrict__ v,
    const float* __restrict__ wq, const float* __restrict__ wk, const float* __restrict__ wv,
    const float* __restrict__ wo,
    bf16_t* __restrict__ qb, bf16_t* __restrict__ kb, bf16_t* __restrict__ vb,
    bf16_t* __restrict__ wqb, bf16_t* __restrict__ wkb, bf16_t* __restrict__ wvb,
    bf16_t* __restrict__ wob)
{
  const size_t M1 = 1048576;
  size_t e = ((size_t)blockIdx.x * 256 + threadIdx.x) * 4;
  const float* src; bf16_t* dst; size_t off;
  if      (e <  4*M1) { src = q;  dst = qb;  off = e;         }
  else if (e <  8*M1) { src = k;  dst = kb;  off = e - 4*M1;  }
  else if (e < 12*M1) { src = v;  dst = vb;  off = e - 8*M1;  }
  else if (e < 13*M1) { src = wq; dst = wqb; off = e - 12*M1; }
  else if (e < 14*M1) { src = wk; dst = wkb; off = e - 13*M1; }
  else if (e < 15*M1) { src = wv; dst = wvb; off = e - 14*M1; }
  else                { src = wo; dst = wob; off = e - 15*M1; }
  float4 f = *reinterpret_cast<const float4*>(src + off);
  bf16x4 o;
  o[0] = (bf16_t)f.x; o[1] = (bf16_t)f.y; o[2] = (bf16_t)f.z; o[3] = (bf16_t)f.w;
  *reinterpret_cast<bf16x4*>(dst + off) = o;
}

// ---------------- GEMM: C[M][N] = A[M][K] * W[N][K]^T (+bias)*scale
// packmode: 0 = linear bf16, 1 = K pack for 32x32 A-frag, 2 = V^T pack for 32x32 A-frag
__device__ __forceinline__ void gemm_body(
    const bf16_t* __restrict__ A, const bf16_t* __restrict__ W,
    const float* __restrict__ bias, bf16_t* __restrict__ outb,
    float* __restrict__ outf, int M, int N, int K, float scale, int packmode)
{
  __shared__ bf16_t As[128 * 32];
  __shared__ bf16_t Bs[128 * 32];
  int tid = threadIdx.x;
  int w = tid >> 6, lane = tid & 63;
  int lr = lane & 15, lg = lane >> 4;
  int wr = w >> 1, wc = w & 1;
  int m0 = blockIdx.x * 128, n0 = blockIdx.y * 128;

  f32x4 acc[4][4];
#pragma unroll
  for (int a = 0; a < 4; ++a)
#pragma unroll
    for (int bq = 0; bq < 4; ++bq) acc[a][bq] = (f32x4){0.f, 0.f, 0.f, 0.f};

  int col_st = (lane & 3) * 8;

  for (int kt = 0; kt < K; kt += 32) {
#pragma unroll
    for (int it = 0; it < 2; ++it) {
      int chunkbase = (w * 2 + it) * 512;
      int row = (w * 2 + it) * 16 + (lane >> 2);
      gload_lds16(A + (size_t)(m0 + row) * K + kt + col_st, &As[chunkbase]);
      gload_lds16(W + (size_t)(n0 + row) * K + kt + col_st, &Bs[chunkbase]);
    }
    __syncthreads();
    bf16x8 af[4], bfv[4];
#pragma unroll
    for (int mf = 0; mf < 4; ++mf)
      af[mf] = *reinterpret_cast<const bf16x8*>(&As[(wr * 64 + mf * 16 + lr) * 32 + lg * 8]);
#pragma unroll
    for (int nf = 0; nf < 4; ++nf)
      bfv[nf] = *reinterpret_cast<const bf16x8*>(&Bs[(wc * 64 + nf * 16 + lr) * 32 + lg * 8]);
#pragma unroll
    for (int mf = 0; mf < 4; ++mf)
#pragma unroll
      for (int nf = 0; nf < 4; ++nf)
        acc[mf][nf] = __builtin_amdgcn_mfma_f32_16x16x32_bf16(af[mf], bfv[nf], acc[mf][nf], 0, 0, 0);
    __syncthreads();
  }

#pragma unroll
  for (int mf = 0; mf < 4; ++mf) {
#pragma unroll
    for (int nf = 0; nf < 4; ++nf) {
      int col = n0 + wc * 64 + nf * 16 + lr;
      float bcol = bias[col];
#pragma unroll
      for (int i = 0; i < 4; ++i) {
        int row = m0 + wr * 64 + mf * 16 + lg * 4 + i;
        float vv = (acc[mf][nf][i] + bcol) * scale;
        if (outf) {
          outf[(size_t)row * N + col] = vv;
        } else if (packmode == 0) {
          outb[(size_t)row * N + col] = (bf16_t)vv;
        } else if (packmode == 1) {
          // K pack: A-frag for mfma_32x32x16. lane = hi*32 + (kv&31),
          // elem j: K[kv][d = ks*16 + hi*8 + j].
          int hh = col >> 6, dh = col & 63;
          int ks = dh >> 4, hi2 = (dh >> 3) & 1, jj = dh & 7;
          int bb2 = row >> 11, sK = row & 2047;
          int bh = bb2 * 16 + hh;
          size_t off = ((size_t)(bh * 64 + (sK >> 5)) * 8 + ks * 2 + hi2) * 256
                     + (size_t)(sK & 31) * 8 + jj;
          outb[off] = (bf16_t)vv;
        } else {
          // V^T pack: A-frag per (t32, s2, db). lane = hi*32 + dlo,
          // elem j: V^T[d = db*32+dlo][kv = t32*32 + s2*16 + hi*8 + j].
          int hh = col >> 6, d = col & 63;
          int db = d >> 5, dlo = d & 31;
          int bb2 = row >> 11, sK = row & 2047;
          int t32 = sK >> 5, kvin = sK & 31;
          int s2 = kvin >> 4, hi2 = (kvin >> 3) & 1, jj = kvin & 7;
          int bh = bb2 * 16 + hh;
          size_t off = ((size_t)(bh * 64 + t32) * 4 + s2 * 2 + db) * 512
                     + (size_t)(hi2 * 32 + dlo) * 8 + jj;
          outb[off] = (bf16_t)vv;
        }
      }
    }
  }
}

__global__ __launch_bounds__(256) void gemm_proj(
    const bf16_t* __restrict__ qb, const bf16_t* __restrict__ kb, const bf16_t* __restrict__ vb,
    const bf16_t* __restrict__ wqb, const bf16_t* __restrict__ wkb, const bf16_t* __restrict__ wvb,
    const float* __restrict__ bq, const float* __restrict__ bk, const float* __restrict__ bv,
    bf16_t* __restrict__ Qp, bf16_t* __restrict__ Kpk, bf16_t* __restrict__ Vpk)
{
  int z = blockIdx.z;
  const bf16_t* A = (z == 0) ? qb : (z == 1) ? kb : vb;
  const bf16_t* W = (z == 0) ? wqb : (z == 1) ? wkb : wvb;
  const float* bias = (z == 0) ? bq : (z == 1) ? bk : bv;
  bf16_t* o = (z == 0) ? Qp : (z == 1) ? Kpk : Vpk;
  // fold 1/sqrt(64) AND log2(e) into Q so attention can use raw exp2
  float scale = (z == 0) ? 0.125f * LOG2E : 1.0f;
  gemm_body(A, W, bias, o, nullptr, BATCH * S_LEN, DMODEL, DMODEL, scale, z);
}

__global__ __launch_bounds__(256) void gemm_out(
    const bf16_t* __restrict__ O, const bf16_t* __restrict__ wob,
    const float* __restrict__ bo, float* __restrict__ out)
{
  gemm_body(O, wob, bo, nullptr, out, BATCH * S_LEN, DMODEL, DMODEL, 1.0f, 0);
}

// ---------------- causal flash attention, 32x32 MFMA, in-register softmax.
// S^T = mfma_32x32x16(K,Q): lane holds q = lane&31, kv = (r&3)+8(r>>2)+4*hi.
// Softmax fully in-reg (15 fmax; shfl only on rare defer-max path). P->PV
// B-frag rebuilt IN REGISTERS: pack 8 dwords, 4 shfl_xor(32) + selects
// (dest lane (q,hi) step s needs p-chunk 4*(2s+hi) from both halves).
// PV = mfma(V^T_frag, P_frag) into two f32x16 (d 0-31 / 32-63).
// NO LDS P round trip, NO barriers in the kv loop.
// Schedule = r12's uniform-trip shape: grid 512 = 32bh x 16qp; 4 waves =
// {q-slice s} x {kv-half hf}; phases {qp, 31-qp}; ~33 trips every wave;
// merge m/l/oacc via stride-35 LDS once per phase.
__global__ __launch_bounds__(256, 2) void attn_fwd(
    const bf16_t* __restrict__ Qp, const bf16_t* __restrict__ Kpk,
    const bf16_t* __restrict__ Vpk, bf16_t* __restrict__ O)
{
  int flat = blockIdx.x;
  int bh = flat & 31, qp = flat >> 5;
  int b = bh >> 4, h = bh & 15;
  int tid = threadIdx.x, wv = tid >> 6, lane = tid & 63;
  int ql = lane & 31, hi = lane >> 5;
  int s = wv >> 1, hf = wv & 1;

  __shared__ float Om[2][64][35];   // [slice][lane][m,l,oacc0[16],oacc1[16]]

  const bf16_t* Kbh = Kpk + (size_t)bh * 131072 + lane * 8;
  const bf16_t* Vbh = Vpk + (size_t)bh * 131072 + lane * 8;

  for (int p = 0; p < 2; ++p) {
    int qt64 = p ? (31 - qp) : qp;
    int qbase = qt64 * 64 + s * 32;
    int q_row = qbase + ql;
    int t_diag = qbase >> 5;
    int t0 = hf ? (qt64 + 1) : 0;
    int t1 = hf ? (2 * qt64 + 2) : (qt64 + 1);
    t1 = (t1 < t_diag + 1) ? t1 : (t_diag + 1);   // skip fully-masked tiles

    // Q B-frags: Q[q=qbase+ql][k = ks*16 + hi*8 + j]
    const bf16_t* Qb = Qp + ((size_t)b * S_LEN + q_row) * DMODEL + h * HDIM + hi * 8;
    bf16x8 qf[4];
#pragma unroll
    for (int ks = 0; ks < 4; ++ks)
      qf[ks] = *reinterpret_cast<const bf16x8*>(Qb + ks * 16);

    f32x16 oacc0 = (f32x16)(0.0f);
    f32x16 oacc1 = (f32x16)(0.0f);
    float m = -1e30f, l = 0.f;

    for (int t = t0; t < t1; ++t) {
      const bf16_t* Kt = Kbh + (size_t)t * 2048;
      const bf16_t* Vt = Vbh + (size_t)t * 2048;

      // ---- fragment loads (8 x 1KB coalesced)
      bf16x8 kf[4], vf[4];
#pragma unroll
      for (int f = 0; f < 4; ++f)
        kf[f] = *reinterpret_cast<const bf16x8*>(Kt + f * 512);
#pragma unroll
      for (int f = 0; f < 4; ++f)
        vf[f] = *reinterpret_cast<const bf16x8*>(Vt + f * 512);

      // ---- S^T = K Q^T : 4 chained 32x32x16 MFMA over D=64
      f32x16 sa = (f32x16)(0.0f);
      __builtin_amdgcn_s_setprio(1);
      sa = __builtin_amdgcn_mfma_f32_32x32x16_bf16(kf[0], qf[0], sa, 0, 0, 0);
      sa = __builtin_amdgcn_mfma_f32_32x32x16_bf16(kf[1], qf[1], sa, 0, 0, 0);
      sa = __builtin_amdgcn_mfma_f32_32x32x16_bf16(kf[2], qf[2], sa, 0, 0, 0);
      sa = __builtin_amdgcn_mfma_f32_32x32x16_bf16(kf[3], qf[3], sa, 0, 0, 0);
      __builtin_amdgcn_s_setprio(0);

      // ---- causal mask on the diagonal 32-tile (kv_local vs ql per lane)
      if (t == t_diag) {
#pragma unroll
        for (int r = 0; r < 16; ++r) {
          int kvl = (r & 3) + 8 * (r >> 2) + 4 * hi;
          if (kvl > ql) sa[r] = -1e30f;
        }
      }

      // ---- defer-max online softmax (no cross-lane on common path)
      float lmax = sa[0];
#pragma unroll
      for (int r = 1; r < 16; ++r) lmax = fmaxf(lmax, sa[r]);
      if (__any(lmax > m + 8.f)) {
        float mx = fmaxf(lmax, __shfl_xor(lmax, 32));
        float mn = fmaxf(m, mx);
        float rsc = __builtin_amdgcn_exp2f(m - mn);
        m = mn; l *= rsc;
        oacc0 *= rsc;
        oacc1 *= rsc;
      }

      float pr[16];
      float psum = 0.f;
#pragma unroll
      for (int r = 0; r < 16; ++r) {
        pr[r] = __builtin_amdgcn_exp2f(sa[r] - m);
        psum += pr[r];
      }
      l += psum;

      // ---- pack P to 8 dwords (pairs along r)
      uint32_t w[8];
#pragma unroll
      for (int kk = 0; kk < 8; ++kk) {
        bf16_t plo = (bf16_t)pr[2 * kk], phi = (bf16_t)pr[2 * kk + 1];
        w[kk] = (uint32_t)__builtin_bit_cast(unsigned short, plo)
              | ((uint32_t)__builtin_bit_cast(unsigned short, phi) << 16);
      }

      // ---- PV: rebuild B-frags in-register (per step s2: 2 shfl + selects)
      __builtin_amdgcn_s_setprio(1);
      {  // s2 = 0: kv_local 0..15, chunks {0 (hi=0) / 1 (hi=1)}
        uint32_t u0  = hi ? w[2] : w[0], u1  = hi ? w[3] : w[1];
        uint32_t sd0 = hi ? w[0] : w[2], sd1 = hi ? w[1] : w[3];
        uint32_t x0 = __shfl_xor(sd0, 32), x1 = __shfl_xor(sd1, 32);
        u32x4 pw = { hi ? x0 : u0, hi ? x1 : u1, hi ? u0 : x0, hi ? u1 : x1 };
        bf16x8 pf = __builtin_bit_cast(bf16x8, pw);
        oacc0 = __builtin_amdgcn_mfma_f32_32x32x16_bf16(vf[0], pf, oacc0, 0, 0, 0);
        oacc1 = __builtin_amdgcn_mfma_f32_32x32x16_bf16(vf[1], pf, oacc1, 0, 0, 0);
      }
      {  // s2 = 1: kv_local 16..31, chunks {2 / 3}
        uint32_t u0  = hi ? w[6] : w[4], u1  = hi ? w[7] : w[5];
        uint32_t sd0 = hi ? w[4] : w[6], sd1 = hi ? w[5] : w[7];
        uint32_t x0 = __shfl_xor(sd0, 32), x1 = __shfl_xor(sd1, 32);
        u32x4 pw = { hi ? x0 : u0, hi ? x1 : u1, hi ? u0 : x0, hi ? u1 : x1 };
        bf16x8 pf = __builtin_bit_cast(bf16x8, pw);
        oacc0 = __builtin_amdgcn_mfma_f32_32x32x16_bf16(vf[2], pf, oacc0, 0, 0, 0);
        oacc1 = __builtin_amdgcn_mfma_f32_32x32x16_bf16(vf[3], pf, oacc1, 0, 0, 0);
      }
      __builtin_amdgcn_s_setprio(0);
    }

    // ---- kv-half merge: hf=1 publishes, hf=0 combines + writes O
    if (hf) {
      Om[s][lane][0] = m;
      Om[s][lane][1] = l;
#pragma unroll
      for (int r = 0; r < 16; ++r) {
        Om[s][lane][2 + r]  = oacc0[r];
        Om[s][lane][18 + r] = oacc1[r];
      }
    }
    __syncthreads();
    if (!hf) {
      float mB = Om[s][lane][0], lB = Om[s][lane][1];
      float mAB = fmaxf(m, mB);
      float fA = __builtin_amdgcn_exp2f(m - mAB);
      float fB = __builtin_amdgcn_exp2f(mB - mAB);
      l = l * fA + lB * fB;
#pragma unroll
      for (int r = 0; r < 16; ++r) {
        oacc0[r] = oacc0[r] * fA + Om[s][lane][2 + r]  * fB;
        oacc1[r] = oacc1[r] * fA + Om[s][lane][18 + r] * fB;
      }
      l += __shfl_xor(l, 32);
      float inv = 1.0f / l;
      bf16_t* ob = O + ((size_t)b * S_LEN + q_row) * DMODEL + h * HDIM;
#pragma unroll
      for (int g = 0; g < 4; ++g) {
        bf16x4 ov0, ov1;
#pragma unroll
        for (int i = 0; i < 4; ++i) {
          ov0[i] = (bf16_t)(oacc0[4 * g + i] * inv);
          ov1[i] = (bf16_t)(oacc1[4 * g + i] * inv);
        }
        *reinterpret_cast<bf16x4*>(ob + 8 * g + 4 * hi)      = ov0;
        *reinterpret_cast<bf16x4*>(ob + 32 + 8 * g + 4 * hi) = ov1;
      }
    }
    __syncthreads();   // Om free for next phase
  }
}

extern "C" void kernel_launch(void* const* d_in, const int* in_sizes, int n_in,
                              void* d_out, int out_size, void* d_ws, size_t ws_size,
                              hipStream_t stream) {
  const float* q  = (const float*)d_in[0];
  const float* k  = (const float*)d_in[1];
  const float* v  = (const float*)d_in[2];
  // d_in[3] = mask (known causal tril; hard-coded)
  const float* Wq = (const float*)d_in[4];
  const float* bq = (const float*)d_in[5];
  const float* Wk = (const float*)d_in[6];
  const float* bk = (const float*)d_in[7];
  const float* Wv = (const float*)d_in[8];
  const float* bv = (const float*)d_in[9];
  const float* Wo = (const float*)d_in[10];
  const float* bo = (const float*)d_in[11];
  float* out = (float*)d_out;

  const size_t MB = 1u << 20;
  char* base = (char*)d_ws;
  bf16_t* qb  = (bf16_t*)(base + 0 * MB);
  bf16_t* kb  = (bf16_t*)(base + 8 * MB);
  bf16_t* vb  = (bf16_t*)(base + 16 * MB);
  bf16_t* wqb = (bf16_t*)(base + 24 * MB);
  bf16_t* wkb = (bf16_t*)(base + 26 * MB);
  bf16_t* wvb = (bf16_t*)(base + 28 * MB);
  bf16_t* wob = (bf16_t*)(base + 30 * MB);
  bf16_t* Qp  = (bf16_t*)(base + 32 * MB);
  bf16_t* Kpk = (bf16_t*)(base + 40 * MB);
  bf16_t* Vpk = (bf16_t*)(base + 48 * MB);
  bf16_t* Ob  = (bf16_t*)(base + 56 * MB);

  convert_all<<<16384, 256, 0, stream>>>(q, k, v, Wq, Wk, Wv, Wo,
                                         qb, kb, vb, wqb, wkb, wvb, wob);
  gemm_proj<<<dim3(32, 8, 3), 256, 0, stream>>>(qb, kb, vb, wqb, wkb, wvb,
                                                bq, bk, bv, Qp, Kpk, Vpk);
  attn_fwd<<<512, 256, 0, stream>>>(Qp, Kpk, Vpk, Ob);
  gemm_out<<<dim3(32, 8), 256, 0, stream>>>(Ob, wob, bo, out);
}